// Round 1
// baseline (676.045 us; speedup 1.0000x reference)
//
#include <hip/hip_runtime.h>
#include <math.h>

// Problem: Bahdanau attention, B=32, T=2048, D=512, U=512, all fp32.
//   proj_v = values @ W1 + b1        [B,T,U]   <- 34.4 GFLOP, dominant
//   proj_q = query @ W2 + b2         [B,1,U]
//   score  = tanh(proj_v + proj_q)@V [B,T,1]   (bV dropped: softmax shift-invariant)
//   w      = softmax(score, axis=T)
//   ctx    = sum_t w * values        [B,D]
// Outputs concat: ctx (16384 floats) then w (65536 floats).
//
// Round 1: correct fp32 baseline. score_kernel = tiled vector-FP32 GEMM with
// fused tanh/V epilogue (no [B,T,U] materialization). MFMA comes next round.

#define B_ 32
#define T_ 2048
#define D_ 512
#define U_ 512
#define M_ (B_ * T_)

// ---------------- proj_q = query @ W2 + b2 ----------------
__global__ __launch_bounds__(256) void projq_kernel(
    const float* __restrict__ query, const float* __restrict__ W2,
    const float* __restrict__ b2, float* __restrict__ projq) {
  const int b = blockIdx.x;
  const int u = blockIdx.y * 256 + threadIdx.x;
  __shared__ float q[D_];
  for (int d = threadIdx.x; d < D_; d += 256) q[d] = query[b * D_ + d];
  __syncthreads();
  float acc = 0.f;
#pragma unroll 8
  for (int d = 0; d < D_; ++d) acc += q[d] * W2[d * U_ + u];
  projq[b * U_ + u] = acc + b2[u];
}

// ---------------- scores: GEMM + tanh/V epilogue ----------------
// Block tile 64(M) x 64(U), K-tile 16. 256 threads as 16x16, 4x4 micro-tile.
// LDS padded to stride 68 (272 B = 16B-aligned rows, bank-spread).
__global__ __launch_bounds__(256) void score_kernel(
    const float* __restrict__ values, const float* __restrict__ W1,
    const float* __restrict__ b1, const float* __restrict__ projq,
    const float* __restrict__ V, float* __restrict__ scores) {
  const int m0 = blockIdx.x * 64;       // row tile (rows = b*T + t)
  const int u0 = blockIdx.y * 64;       // col tile
  const int b = m0 >> 11;               // 64 | 2048 => whole tile same batch
  const int tid = threadIdx.x;
  const int tx = tid & 15;              // u-group
  const int ty = tid >> 4;              // m-group

  __shared__ float As[16][68];          // As[k][m]
  __shared__ float Bs[16][68];          // Bs[k][u]
  __shared__ float red[64][17];

  float c[4][4] = {};

  // A-tile load mapping: thread -> (row aml, k-quad ak4), float4 along K
  const int aml = tid >> 2;             // 0..63
  const int ak4 = (tid & 3) << 2;       // 0,4,8,12
  // B-tile load mapping: thread -> (k bkl, u-quad bu4), float4 along U
  const int bkl = tid >> 4;             // 0..15
  const int bu4 = (tid & 15) << 2;      // 0..60

  const float* aptr = values + (long)(m0 + aml) * D_ + ak4;
  const float* bptr = W1 + (long)bkl * U_ + u0 + bu4;

  for (int k0 = 0; k0 < D_; k0 += 16) {
    const float4 av = *(const float4*)(aptr + k0);
    const float4 bv = *(const float4*)(bptr + (long)k0 * U_);
    As[ak4 + 0][aml] = av.x;
    As[ak4 + 1][aml] = av.y;
    As[ak4 + 2][aml] = av.z;
    As[ak4 + 3][aml] = av.w;
    *(float4*)&Bs[bkl][bu4] = bv;
    __syncthreads();
#pragma unroll
    for (int kk = 0; kk < 16; ++kk) {
      const float4 a = *(const float4*)&As[kk][ty * 4];
      const float4 w = *(const float4*)&Bs[kk][tx * 4];
      c[0][0] += a.x * w.x; c[0][1] += a.x * w.y; c[0][2] += a.x * w.z; c[0][3] += a.x * w.w;
      c[1][0] += a.y * w.x; c[1][1] += a.y * w.y; c[1][2] += a.y * w.z; c[1][3] += a.y * w.w;
      c[2][0] += a.z * w.x; c[2][1] += a.z * w.y; c[2][2] += a.z * w.z; c[2][3] += a.z * w.w;
      c[3][0] += a.w * w.x; c[3][1] += a.w * w.y; c[3][2] += a.w * w.z; c[3][3] += a.w * w.w;
    }
    __syncthreads();
  }

  // epilogue: sum_j tanh(c + b1[u] + projq[b,u]) * V[u], reduce over tx
  float pre[4], vv[4];
#pragma unroll
  for (int j = 0; j < 4; ++j) {
    const int u = u0 + tx * 4 + j;
    pre[j] = b1[u] + projq[b * U_ + u];
    vv[j] = V[u];
  }
#pragma unroll
  for (int i = 0; i < 4; ++i) {
    float s = 0.f;
#pragma unroll
    for (int j = 0; j < 4; ++j) s += tanhf(c[i][j] + pre[j]) * vv[j];
    red[ty * 4 + i][tx] = s;
  }
  __syncthreads();
  if (tid < 64) {
    float s = 0.f;
#pragma unroll
    for (int x = 0; x < 16; ++x) s += red[tid][x];
    atomicAdd(scores + m0 + tid, s);   // partial over this u-block
  }
}

// ---------------- softmax over T per batch ----------------
__global__ __launch_bounds__(256) void softmax_kernel(
    const float* __restrict__ scores, float* __restrict__ weights) {
  const int b = blockIdx.x;
  const int tid = threadIdx.x;
  float v[8];
  float mx = -INFINITY;
#pragma unroll
  for (int i = 0; i < 8; ++i) {
    v[i] = scores[b * T_ + i * 256 + tid];
    mx = fmaxf(mx, v[i]);
  }
#pragma unroll
  for (int off = 32; off > 0; off >>= 1) mx = fmaxf(mx, __shfl_down(mx, off));
  __shared__ float sm[4], ss[4];
  if ((tid & 63) == 0) sm[tid >> 6] = mx;
  __syncthreads();
  mx = fmaxf(fmaxf(sm[0], sm[1]), fmaxf(sm[2], sm[3]));
  float sum = 0.f;
#pragma unroll
  for (int i = 0; i < 8; ++i) {
    v[i] = __expf(v[i] - mx);
    sum += v[i];
  }
#pragma unroll
  for (int off = 32; off > 0; off >>= 1) sum += __shfl_down(sum, off);
  if ((tid & 63) == 0) ss[tid >> 6] = sum;
  __syncthreads();
  const float inv = 1.f / (ss[0] + ss[1] + ss[2] + ss[3]);
#pragma unroll
  for (int i = 0; i < 8; ++i) weights[b * T_ + i * 256 + tid] = v[i] * inv;
}

// ---------------- context = sum_t w * values ----------------
__global__ __launch_bounds__(256) void context_kernel(
    const float* __restrict__ values, const float* __restrict__ weights,
    float* __restrict__ context) {
  const int b = blockIdx.x;
  const int t0 = blockIdx.y * 256;
  const int tid = threadIdx.x;
  __shared__ float w[256];
  w[tid] = weights[b * T_ + t0 + tid];
  __syncthreads();
  float2 acc = make_float2(0.f, 0.f);
  const float2* vp = (const float2*)(values + (long)(b * T_ + t0) * D_) + tid;
#pragma unroll 4
  for (int t = 0; t < 256; ++t) {
    const float2 x = vp[(long)t * (D_ / 2)];
    acc.x += w[t] * x.x;
    acc.y += w[t] * x.y;
  }
  atomicAdd(context + b * D_ + tid * 2 + 0, acc.x);
  atomicAdd(context + b * D_ + tid * 2 + 1, acc.y);
}

extern "C" void kernel_launch(void* const* d_in, const int* in_sizes, int n_in,
                              void* d_out, int out_size, void* d_ws, size_t ws_size,
                              hipStream_t stream) {
  const float* values = (const float*)d_in[0];
  const float* query = (const float*)d_in[1];
  const float* W1 = (const float*)d_in[2];
  const float* b1 = (const float*)d_in[3];
  const float* W2 = (const float*)d_in[4];
  const float* b2 = (const float*)d_in[5];
  const float* V = (const float*)d_in[6];
  // d_in[7] = bV: unused — softmax(score + c) == softmax(score).

  float* out = (float*)d_out;
  float* context = out;            // [32,512]
  float* weights = out + B_ * D_;  // [32,2048]
  float* projq = (float*)d_ws;     // [32,512]
  float* scores = projq + B_ * U_; // [32,2048]

  hipMemsetAsync(scores, 0, M_ * sizeof(float), stream);
  hipMemsetAsync(context, 0, B_ * D_ * sizeof(float), stream);

  projq_kernel<<<dim3(B_, U_ / 256), 256, 0, stream>>>(query, W2, b2, projq);
  score_kernel<<<dim3(M_ / 64, U_ / 64), 256, 0, stream>>>(values, W1, b1, projq, V, scores);
  softmax_kernel<<<B_, 256, 0, stream>>>(scores, weights);
  context_kernel<<<dim3(B_, T_ / 256), 256, 0, stream>>>(values, weights, context);
}

// Round 2
// 360.973 us; speedup vs baseline: 1.8728x; 1.8728x over previous
//
#include <hip/hip_runtime.h>
#include <math.h>

// Bahdanau attention, B=32, T=2048, D=512, U=512, fp32 in/out.
// Round 2: score GEMM -> f16 MFMA (16x16x32), in-kernel fp32->f16 staging.
// f16 chosen over bf16 for 8x mantissa accuracy at identical MFMA rate.

#define B_ 32
#define T_ 2048
#define D_ 512
#define U_ 512
#define M_ (B_ * T_)

typedef _Float16 half8 __attribute__((ext_vector_type(8)));
typedef float floatx4 __attribute__((ext_vector_type(4)));

// ---------------- proj_q = query @ W2 + b2 ----------------
__global__ __launch_bounds__(256) void projq_kernel(
    const float* __restrict__ query, const float* __restrict__ W2,
    const float* __restrict__ b2, float* __restrict__ projq) {
  const int b = blockIdx.x;
  const int u = blockIdx.y * 256 + threadIdx.x;
  __shared__ float q[D_];
  for (int d = threadIdx.x; d < D_; d += 256) q[d] = query[b * D_ + d];
  __syncthreads();
  float acc = 0.f;
#pragma unroll 8
  for (int d = 0; d < D_; ++d) acc += q[d] * W2[d * U_ + u];
  projq[b * U_ + u] = acc + b2[u];
}

// ---------------- scores: f16 MFMA GEMM + tanh/V epilogue ----------------
// Tile 128(M) x 128(U), BK=32. 256 threads = 4 waves in 2x2, each wave 64x64
// via 4x4 grid of 16x16x32 MFMA. A staged [m][k] (k-contig), B staged
// transposed [n][k] (k-contig) so both fragments are single ds_read_b128.
// Fragment layouts (verified, learn_hip): A[m=lane&15][k=(lane>>4)*8+j],
// B[k=(lane>>4)*8+j][n=lane&15], C[row=(lane>>4)*4+reg][col=lane&15].
__global__ __launch_bounds__(256) void score_mfma_kernel(
    const float* __restrict__ values, const float* __restrict__ W1,
    const float* __restrict__ b1, const float* __restrict__ projq,
    const float* __restrict__ V, float* __restrict__ scores) {
  const int m0 = blockIdx.x * 128;
  const int u0 = blockIdx.y * 128;
  const int b = blockIdx.x >> 4;  // 2048/128 = 16 row-blocks per batch
  const int tid = threadIdx.x;

  __shared__ alignas(16) _Float16 As[128 * 32];  // As[m][k]
  __shared__ alignas(16) _Float16 Bs[128 * 32];  // Bs[n][k]

  const int lane = tid & 63;
  const int w = tid >> 6;
  const int wm = (w & 1) * 64;
  const int wn = (w >> 1) * 64;
  const int ln = lane & 15;
  const int lq = lane >> 4;

  floatx4 acc[4][4] = {};

  // Staging map: thread -> (row/col srow, k-half skoff), 16 k's each.
  const int srow = tid >> 1;
  const int skoff = (tid & 1) * 16;
  const float* aptr = values + (long)(m0 + srow) * D_ + skoff;
  const float* bptr = W1 + u0 + srow;  // column n=u0+srow, stride U_ over k

  for (int k0 = 0; k0 < D_; k0 += 32) {
    // A-tile: 4 float4 loads, convert, two 16B LDS stores
    const float4 a0 = *(const float4*)(aptr + k0);
    const float4 a1 = *(const float4*)(aptr + k0 + 4);
    const float4 a2 = *(const float4*)(aptr + k0 + 8);
    const float4 a3 = *(const float4*)(aptr + k0 + 12);
    half8 ha0 = {(_Float16)a0.x, (_Float16)a0.y, (_Float16)a0.z, (_Float16)a0.w,
                 (_Float16)a1.x, (_Float16)a1.y, (_Float16)a1.z, (_Float16)a1.w};
    half8 ha1 = {(_Float16)a2.x, (_Float16)a2.y, (_Float16)a2.z, (_Float16)a2.w,
                 (_Float16)a3.x, (_Float16)a3.y, (_Float16)a3.z, (_Float16)a3.w};
    // B-tile (transposed): 16 strided scalar loads (coalesced across lanes)
    float bt[16];
#pragma unroll
    for (int kk = 0; kk < 16; ++kk)
      bt[kk] = bptr[(long)(k0 + skoff + kk) * U_];
    half8 hb0 = {(_Float16)bt[0], (_Float16)bt[1], (_Float16)bt[2], (_Float16)bt[3],
                 (_Float16)bt[4], (_Float16)bt[5], (_Float16)bt[6], (_Float16)bt[7]};
    half8 hb1 = {(_Float16)bt[8], (_Float16)bt[9], (_Float16)bt[10], (_Float16)bt[11],
                 (_Float16)bt[12], (_Float16)bt[13], (_Float16)bt[14], (_Float16)bt[15]};

    *(half8*)&As[srow * 32 + skoff] = ha0;
    *(half8*)&As[srow * 32 + skoff + 8] = ha1;
    *(half8*)&Bs[srow * 32 + skoff] = hb0;
    *(half8*)&Bs[srow * 32 + skoff + 8] = hb1;
    __syncthreads();

    half8 af[4], bf[4];
#pragma unroll
    for (int i = 0; i < 4; ++i) {
      af[i] = *(const half8*)&As[(wm + i * 16 + ln) * 32 + lq * 8];
      bf[i] = *(const half8*)&Bs[(wn + i * 16 + ln) * 32 + lq * 8];
    }
#pragma unroll
    for (int mi = 0; mi < 4; ++mi)
#pragma unroll
      for (int ni = 0; ni < 4; ++ni)
        acc[mi][ni] = __builtin_amdgcn_mfma_f32_16x16x32_f16(
            af[mi], bf[ni], acc[mi][ni], 0, 0, 0);
    __syncthreads();
  }

  // Epilogue: s[row] += sum_col tanh(c + b1[u] + projq[b,u]) * V[u]
  float pre[4], vv[4];
#pragma unroll
  for (int ni = 0; ni < 4; ++ni) {
    const int u = u0 + wn + ni * 16 + ln;
    pre[ni] = b1[u] + projq[b * U_ + u];
    vv[ni] = V[u];
  }
#pragma unroll
  for (int mi = 0; mi < 4; ++mi) {
#pragma unroll
    for (int r = 0; r < 4; ++r) {
      float t = 0.f;
#pragma unroll
      for (int ni = 0; ni < 4; ++ni)
        t += tanhf(acc[mi][ni][r] + pre[ni]) * vv[ni];
      // reduce over the 16-lane column group
      t += __shfl_xor(t, 1);
      t += __shfl_xor(t, 2);
      t += __shfl_xor(t, 4);
      t += __shfl_xor(t, 8);
      if (ln == mi * 4 + r)  // one atomic per lane
        atomicAdd(scores + m0 + wm + mi * 16 + lq * 4 + r, t);
    }
  }
}

// ---------------- softmax over T per batch ----------------
__global__ __launch_bounds__(256) void softmax_kernel(
    const float* __restrict__ scores, float* __restrict__ weights) {
  const int b = blockIdx.x;
  const int tid = threadIdx.x;
  float v[8];
  float mx = -INFINITY;
#pragma unroll
  for (int i = 0; i < 8; ++i) {
    v[i] = scores[b * T_ + i * 256 + tid];
    mx = fmaxf(mx, v[i]);
  }
#pragma unroll
  for (int off = 32; off > 0; off >>= 1) mx = fmaxf(mx, __shfl_down(mx, off));
  __shared__ float sm[4], ss[4];
  if ((tid & 63) == 0) sm[tid >> 6] = mx;
  __syncthreads();
  mx = fmaxf(fmaxf(sm[0], sm[1]), fmaxf(sm[2], sm[3]));
  float sum = 0.f;
#pragma unroll
  for (int i = 0; i < 8; ++i) {
    v[i] = __expf(v[i] - mx);
    sum += v[i];
  }
#pragma unroll
  for (int off = 32; off > 0; off >>= 1) sum += __shfl_down(sum, off);
  if ((tid & 63) == 0) ss[tid >> 6] = sum;
  __syncthreads();
  const float inv = 1.f / (ss[0] + ss[1] + ss[2] + ss[3]);
#pragma unroll
  for (int i = 0; i < 8; ++i) weights[b * T_ + i * 256 + tid] = v[i] * inv;
}

// ---------------- context = sum_t w * values ----------------
// 64-row t-tiles -> 1024 blocks (round 1's 256 was occupancy-starved).
__global__ __launch_bounds__(256) void context_kernel(
    const float* __restrict__ values, const float* __restrict__ weights,
    float* __restrict__ context) {
  const int b = blockIdx.x;
  const int t0 = blockIdx.y * 64;
  const int tid = threadIdx.x;
  __shared__ float w[64];
  if (tid < 64) w[tid] = weights[b * T_ + t0 + tid];
  __syncthreads();
  float2 acc = make_float2(0.f, 0.f);
  const float2* vp = (const float2*)(values + (long)(b * T_ + t0) * D_) + tid;
#pragma unroll 4
  for (int t = 0; t < 64; ++t) {
    const float2 x = vp[(long)t * (D_ / 2)];
    acc.x += w[t] * x.x;
    acc.y += w[t] * x.y;
  }
  atomicAdd(context + b * D_ + tid * 2 + 0, acc.x);
  atomicAdd(context + b * D_ + tid * 2 + 1, acc.y);
}

extern "C" void kernel_launch(void* const* d_in, const int* in_sizes, int n_in,
                              void* d_out, int out_size, void* d_ws, size_t ws_size,
                              hipStream_t stream) {
  const float* values = (const float*)d_in[0];
  const float* query = (const float*)d_in[1];
  const float* W1 = (const float*)d_in[2];
  const float* b1 = (const float*)d_in[3];
  const float* W2 = (const float*)d_in[4];
  const float* b2 = (const float*)d_in[5];
  const float* V = (const float*)d_in[6];
  // d_in[7] = bV: unused — softmax is shift-invariant.

  float* out = (float*)d_out;
  float* context = out;            // [32,512]
  float* weights = out + B_ * D_;  // [32,2048]
  float* projq = (float*)d_ws;     // [32,512]
  float* scores = projq + B_ * U_; // [32,2048]

  hipMemsetAsync(scores, 0, M_ * sizeof(float), stream);
  hipMemsetAsync(context, 0, B_ * D_ * sizeof(float), stream);

  projq_kernel<<<dim3(B_, U_ / 256), 256, 0, stream>>>(query, W2, b2, projq);
  score_mfma_kernel<<<dim3(M_ / 128, U_ / 128), 256, 0, stream>>>(
      values, W1, b1, projq, V, scores);
  softmax_kernel<<<B_, 256, 0, stream>>>(scores, weights);
  context_kernel<<<dim3(B_, T_ / 64), 256, 0, stream>>>(values, weights, context);
}